// Round 7
// baseline (5229.188 us; speedup 1.0000x reference)
//
#include <hip/hip_runtime.h>
#include <stdint.h>

#define NLAYER 6
#define BATCH  128
#define HID    256
#define TSEQ   512
#define INFEAT 128
#define DEPTH  4          // ring slots per layer (power of 2)
#define OUTN   10

typedef __attribute__((ext_vector_type(8))) short bf16x8;
typedef __attribute__((ext_vector_type(4))) float f32x4;
typedef unsigned long long u64;

__device__ __forceinline__ short f2bf(float f) {
  union { float f; uint32_t u; } v; v.f = f;
  uint32_t r = v.u + 0x7fffu + ((v.u >> 16) & 1u);   // RNE
  return (short)(r >> 16);
}
__device__ __forceinline__ float bf2f(uint32_t b) {
  union { uint32_t u; float f; } v; v.u = b << 16;
  return v.f;
}
__device__ __forceinline__ bf16x8 cvt8(const float* p) {
  f32x4 a = *(const f32x4*)p;
  f32x4 b = *(const f32x4*)(p + 4);
  bf16x8 r;
  r[0] = f2bf(a[0]); r[1] = f2bf(a[1]); r[2] = f2bf(a[2]); r[3] = f2bf(a[3]);
  r[4] = f2bf(b[0]); r[5] = f2bf(b[1]); r[6] = f2bf(b[2]); r[7] = f2bf(b[3]);
  return r;
}
__device__ __forceinline__ float sigm(float x)  { return 1.0f / (1.0f + __expf(-x)); }
__device__ __forceinline__ float tanhff(float x){ return 1.0f - 2.0f / (__expf(2.0f * x) + 1.0f); }

__device__ __forceinline__ u64 ld64(const u64* p) {
  return __hip_atomic_load(p, __ATOMIC_RELAXED, __HIP_MEMORY_SCOPE_AGENT);
}
__device__ __forceinline__ void st64(u64* p, u64 v) {
  __hip_atomic_store(p, v, __ATOMIC_RELAXED, __HIP_MEMORY_SCOPE_AGENT);
}
__device__ __forceinline__ void st16(uint16_t* p, uint16_t v) {
  __hip_atomic_store(p, v, __ATOMIC_RELAXED, __HIP_MEMORY_SCOPE_AGENT);
}

// Ring record: u64 = [tag:16][pad:16][h(2u+1):bf16][h(2u):bf16]  (low u32 = 2 units)
// One atomic store publishes data+validity together: no drains, no flags.
// Tags are t+1 (1..512); 0xAAAA poison never matches; DEPTH=4 generations
// have distinct tags, so slot reuse is unambiguous.

// 192 blocks x 256 threads: 6 layers x 4 batch-slices(32 rows) x 8 cg(32 units).
// 4 independent waves: wm (16-row half) x wu (16-unit half). No in-loop barriers.
// W_hh register-resident (critical path); W_ih in LDS, lane-major (conflict-free).
__global__ void __launch_bounds__(256, 1)
lstm_pipeline(const float* __restrict__ xin, const float* __restrict__ h0,
              const float* __restrict__ c0,  const float* __restrict__ wih,
              const float* __restrict__ whh, const float* __restrict__ bih,
              const float* __restrict__ bhh, const float* __restrict__ fcw,
              const float* __restrict__ fcb, float* __restrict__ out,
              uint16_t* prog, u64* ring)
{
  const int bid  = blockIdx.x;
  const int xcd  = bid & 7;
  const int slot = bid >> 3;
  const int grp  = (slot >> 3) * 8 + xcd;    // (layer,bslice) group: siblings share XCD guess
  const int cg   = slot & 7;
  const int l  = grp >> 2;
  const int bs = grp & 3;

  const int tid  = threadIdx.x;
  const int wv   = tid >> 6, lane = tid & 63;
  const int wm   = wv & 1,  wu   = wv >> 1;
  const int l15  = lane & 15, l4 = lane >> 4;

  // ---- W_ih -> LDS, lane-major fragment layout: idx = ((gt*8+kk)*4+l4)*32 + unit ----
  __shared__ bf16x8 lds_wih[4096];           // 64 KB
  {
    const float* W = wih + (size_t)l * 1024 * 256;
    for (int lin = tid; lin < 4096; lin += 256) {
      const int u5  = lin & 31;
      const int l4s = (lin >> 5) & 3;
      const int kk  = (lin >> 7) & 7;
      const int gt  = lin >> 10;
      const int row = gt * 256 + cg * 32 + u5;
      lds_wih[lin] = cvt8(W + (size_t)row * 256 + kk * 32 + l4s * 8);
    }
  }

  // ---- W_hh register-resident: wh[gate][kk] (128 VGPR) ----
  bf16x8 wh[4][8];
  float  bias[4];
  {
    const float* W = whh + (size_t)l * 1024 * 256;
#pragma unroll
    for (int gt = 0; gt < 4; ++gt) {
      const int Rg = gt * 256 + cg * 32 + wu * 16 + l15;
      const float* rp = W + (size_t)Rg * 256 + l4 * 8;
#pragma unroll
      for (int kk = 0; kk < 8; ++kk)
        wh[gt][kk] = cvt8(rp + kk * 32);
      bias[gt] = bih[l * 1024 + Rg] + bhh[l * 1024 + Rg];
    }
  }
  __syncthreads();   // LDS ready (only barrier in the kernel)

  const int ucol  = cg * 32 + wu * 16 + l15;
  const int mrowA = bs * 32 + wm * 16 + l15;
  const int mrow0 = bs * 32 + wm * 16 + l4 * 4;

  float c[4];
#pragma unroll
  for (int j = 0; j < 4; ++j)
    c[j] = c0[((size_t)l * BATCH + (mrow0 + j)) * HID + ucol];

  u64*       ringO = ring + (size_t)l * DEPTH * BATCH * 128;
  const u64* ringL = ringO;
  const u64* ringX = (l > 0) ? ring + (size_t)(l - 1) * DEPTH * BATCH * 128 : nullptr;

  uint16_t* progOwn = prog + (l * 4 + bs) * 32;
  const u64* progCons = (l < 5) ? (const u64*)(prog + ((l + 1) * 4 + bs) * 32) : nullptr;

  const int srow = bs * 32 + wm * 16 + 15;     // sentinel row (last row of our wm half)

  for (int t = 0; t < TSEQ; ++t) {
    // ---- publish progress (fire-and-forget; consumed only as backpressure) ----
    if (lane == 0)
      st16(progOwn + (cg * 4 + wv), (uint16_t)t);

    // ---- sentinel rendezvous: one record per producer wave, 1 load/lane ----
    // lanes 0..15: h producers (own layer, t-1); lanes 16..31: x producers (l-1, t)
    {
      const bool isH = (lane < 16), isX = (lane >= 16 && lane < 32);
      const bool needS = (isH && t > 0) || (isX && l > 0);
      const u64* sp = ringL;     // safe default
      u64 stag = 0;
      if (isH && t > 0) {
        const int cgp = lane >> 1, wup = lane & 1;
        sp = ringL + (((size_t)((t - 1) & (DEPTH - 1)) * BATCH + srow) * 128 + cgp * 16 + wup * 8 + 7);
        stag = (u64)t;
      } else if (isX && l > 0) {
        const int i = lane - 16, cgp = i >> 1, wup = i & 1;
        sp = ringX + (((size_t)(t & (DEPTH - 1)) * BATCH + srow) * 128 + cgp * 16 + wup * 8 + 7);
        stag = (u64)(t + 1);
      }
      if (t > 0 || l > 0) {
        for (;;) {
          int ok = 1;
          if (needS) ok = ((ld64(sp) >> 48) == stag);
          if (__all(ok)) break;
        }
      }
    }

    f32x4 acc[4];
#pragma unroll
    for (int gt = 0; gt < 4; ++gt) {
      f32x4 a = {bias[gt], bias[gt], bias[gt], bias[gt]};
      acc[gt] = a;
    }

    // ---- x set: load + tag-verify (retry is rare: sentinels already passed) ----
    const int bcol = wu * 16 + l15;
    if (l == 0) {
      const float* xp = xin + ((size_t)mrowA * TSEQ + t) * INFEAT + l4 * 8;
#pragma unroll
      for (int kk = 0; kk < 4; ++kk) {          // kk 4..7 hit the zero-pad: skip
        bf16x8 axr = cvt8(xp + kk * 32);
#pragma unroll
        for (int gt = 0; gt < 4; ++gt)
          acc[gt] = __builtin_amdgcn_mfma_f32_16x16x32_bf16(
              axr, lds_wih[((gt * 8 + kk) * 4 + l4) * 32 + bcol], acc[gt], 0, 0, 0);
      }
    } else {
      const u64* xb = ringX + ((size_t)(t & (DEPTH - 1)) * BATCH + mrowA) * 128 + l4 * 4;
      const u64 tagX = (u64)(t + 1);
      bf16x8 ax[8];
      for (;;) {
        u64 bad = 0;
#pragma unroll
        for (int kk = 0; kk < 8; ++kk) {
          union { uint32_t w[4]; bf16x8 v; } u;
#pragma unroll
          for (int j = 0; j < 4; ++j) {
            u64 r = ld64(xb + kk * 16 + j);
            bad |= (r >> 48) ^ tagX;
            u.w[j] = (uint32_t)r;
          }
          ax[kk] = u.v;
        }
        if (__all(bad == 0)) break;
      }
#pragma unroll
      for (int kk = 0; kk < 8; ++kk)
#pragma unroll
        for (int gt = 0; gt < 4; ++gt)
          acc[gt] = __builtin_amdgcn_mfma_f32_16x16x32_bf16(
              ax[kk], lds_wih[((gt * 8 + kk) * 4 + l4) * 32 + bcol], acc[gt], 0, 0, 0);
    }

    // ---- h set ----
    if (t == 0) {
      const float* hp = h0 + ((size_t)l * BATCH + mrowA) * HID + l4 * 8;
#pragma unroll
      for (int kk = 0; kk < 8; ++kk) {
        bf16x8 af = cvt8(hp + kk * 32);
#pragma unroll
        for (int gt = 0; gt < 4; ++gt)
          acc[gt] = __builtin_amdgcn_mfma_f32_16x16x32_bf16(af, wh[gt][kk], acc[gt], 0, 0, 0);
      }
    } else {
      const u64* hb = ringL + ((size_t)((t - 1) & (DEPTH - 1)) * BATCH + mrowA) * 128 + l4 * 4;
      const u64 tagH = (u64)t;
      bf16x8 ah[8];
      for (;;) {
        u64 bad = 0;
#pragma unroll
        for (int kk = 0; kk < 8; ++kk) {
          union { uint32_t w[4]; bf16x8 v; } u;
#pragma unroll
          for (int j = 0; j < 4; ++j) {
            u64 r = ld64(hb + kk * 16 + j);
            bad |= (r >> 48) ^ tagH;
            u.w[j] = (uint32_t)r;
          }
          ah[kk] = u.v;
        }
        if (__all(bad == 0)) break;
      }
#pragma unroll
      for (int kk = 0; kk < 8; ++kk)
#pragma unroll
        for (int gt = 0; gt < 4; ++gt)
          acc[gt] = __builtin_amdgcn_mfma_f32_16x16x32_bf16(ah[kk], wh[gt][kk], acc[gt], 0, 0, 0);
    }

    // ---- backpressure (x consumers of our ring): min progress(l+1) >= t-3 ----
    if (l < 5 && t >= DEPTH) {
      const int need = t - (DEPTH - 1);
      for (;;) {
        int mn = 0x7fffffff;
#pragma unroll
        for (int q = 0; q < 8; ++q) {
          u64 v = ld64(progCons + q);
          mn = min(mn, (int)(v & 0xffff));
          mn = min(mn, (int)((v >> 16) & 0xffff));
          mn = min(mn, (int)((v >> 32) & 0xffff));
          mn = min(mn, (int)((v >> 48) & 0xffff));
        }
        if (mn >= need) break;
        __builtin_amdgcn_s_sleep(2);
      }
    }

    // ---- gates, state, tagged h publish (fire-and-forget) ----
    uint32_t hv16[4];
#pragma unroll
    for (int j = 0; j < 4; ++j) {
      float iv = sigm(acc[0][j]);
      float fv = sigm(acc[1][j]);
      float gv = tanhff(acc[2][j]);
      float ov = sigm(acc[3][j]);
      float cc = fv * c[j] + iv * gv;
      c[j] = cc;
      float hv = ov * tanhff(cc);
      hv16[j] = (uint32_t)(uint16_t)f2bf(hv);
    }
    {
      const uint32_t own01 = hv16[0] | (hv16[1] << 16);
      const uint32_t own23 = hv16[2] | (hv16[3] << 16);
      const uint32_t par01 = (uint32_t)__shfl_xor((int)own01, 1);
      const uint32_t par23 = (uint32_t)__shfl_xor((int)own23, 1);
      const u64 tagS = (u64)(t + 1) << 48;
      uint32_t d0, d1; int j0;
      if ((l15 & 1) == 0) {
        d0 = (own01 & 0xffffu) | (par01 << 16);
        d1 = (own01 >> 16)     | (par01 & 0xffff0000u);
        j0 = 0;
      } else {
        d0 = (par23 & 0xffffu) | (own23 << 16);
        d1 = (par23 >> 16)     | (own23 & 0xffff0000u);
        j0 = 2;
      }
      u64* rp = ringO + ((size_t)(t & (DEPTH - 1)) * BATCH + (mrow0 + j0)) * 128 + (ucol >> 1);
      st64(rp,       (u64)d0 | tagS);
      st64(rp + 128, (u64)d1 | tagS);
    }
  }

  // ---------------- FC head: one WG per batch slice ----------------
  if (l == 5 && cg == 0) {
    const u64* hsl = ring + (size_t)5 * DEPTH * BATCH * 128
                   + ((size_t)((TSEQ - 1) & (DEPTH - 1)) * BATCH) * 128;
    for (int p = tid; p < 32 * OUTN; p += 256) {
      const int mr = bs * 32 + p / OUTN, oc = p % OUTN;
      float a = fcb[oc];
      const u64* hr = hsl + (size_t)mr * 128;
      const float* wr = fcw + oc * HID;
      for (int up = 0; up < 128; ++up) {
        u64 r = ld64(hr + up);
        while ((r >> 48) != (u64)TSEQ) r = ld64(hr + up);
        a += bf2f((uint32_t)(r & 0xffff))         * wr[2 * up]
           + bf2f((uint32_t)((r >> 16) & 0xffff)) * wr[2 * up + 1];
      }
      out[mr * OUTN + oc] = a;
    }
  }
}

extern "C" void kernel_launch(void* const* d_in, const int* in_sizes, int n_in,
                              void* d_out, int out_size, void* d_ws, size_t ws_size,
                              hipStream_t stream) {
  const float* xin = (const float*)d_in[0];
  const float* h0  = (const float*)d_in[1];
  const float* c0  = (const float*)d_in[2];
  const float* wih = (const float*)d_in[3];
  const float* whh = (const float*)d_in[4];
  const float* bih = (const float*)d_in[5];
  const float* bhh = (const float*)d_in[6];
  const float* fcw = (const float*)d_in[7];
  const float* fcb = (const float*)d_in[8];
  float* out = (float*)d_out;

  // prog: 24 records x 32 u16 = 1.5 KB (zeroed each launch).
  // ring: 6 layers x 4 slots x 128 rows x 128 upairs x 8B = 3 MB (poison 0xAAAA
  // never matches tags 1..512 -> no init needed).
  uint16_t* prog = (uint16_t*)d_ws;
  u64* ring = (u64*)((char*)d_ws + 0x10000);

  hipMemsetAsync(d_ws, 0, 4096, stream);
  lstm_pipeline<<<dim3(192), dim3(256), 0, stream>>>(
      xin, h0, c0, wih, whh, bih, bhh, fcw, fcb, out, prog, ring);
}